// Round 1
// baseline (887.954 us; speedup 1.0000x reference)
//
#include <hip/hip_runtime.h>
#include <cstdint>
#include <cstddef>

#define BB 8
#define NN 4096
#define IDIM 6
#define DIMS 64
#define KNB 32
#define BN (BB * NN)

static constexpr float LN_EPS = 1e-5f;

__device__ __forceinline__ float wsum64(float v) {
#pragma unroll
    for (int off = 32; off > 0; off >>= 1)
        v += __shfl_xor(v, off, 64);
    return v;
}

// Kernel 1: per point p (one wave = 64 lanes = 64 dims)
//   x = relu(LN(inputs@W1 + b1))          (6-dim contraction)
//   a = x @ W2[0:64]   (the "ball" part, gatherable)
//   c = x @ W2[64:128] + b2 - a           (the per-center constant part)
//   Sa = sum_d a[d]                       (for free LN means downstream)
__global__ __launch_bounds__(256, 4) void k1_feat(
    const float* __restrict__ inp, const float* __restrict__ W1,
    const float* __restrict__ b1, const float* __restrict__ g1,
    const float* __restrict__ be1, const float* __restrict__ W2,
    const float* __restrict__ b2,
    float* __restrict__ a_buf, float* __restrict__ c_buf,
    float* __restrict__ Sa_buf)
{
    const int lane = threadIdx.x & 63;
    const int p = (blockIdx.x * 256 + threadIdx.x) >> 6;  // point id 0..BN-1
    const float* ip = inp + (size_t)p * IDIM;
    float h = b1[lane];
#pragma unroll
    for (int j = 0; j < IDIM; ++j)
        h = fmaf(ip[j], W1[j * DIMS + lane], h);
    float mean = wsum64(h) * (1.0f / DIMS);
    float d = h - mean;
    float var = wsum64(d * d) * (1.0f / DIMS);
    float x = fmaxf(d * rsqrtf(var + LN_EPS) * g1[lane] + be1[lane], 0.0f);

    float a = 0.0f, cp = 0.0f;
#pragma unroll 8
    for (int j = 0; j < DIMS; ++j) {
        float xj = __shfl(x, j, 64);
        a  = fmaf(xj, W2[j * DIMS + lane], a);
        cp = fmaf(xj, W2[(DIMS + j) * DIMS + lane], cp);
    }
    float c = cp + b2[lane] - a;
    a_buf[(size_t)p * DIMS + lane] = a;
    c_buf[(size_t)p * DIMS + lane] = c;
    float sa = wsum64(a);
    if (lane == 0) Sa_buf[p] = sa;
}

// Kernel 2: query_ball. One wave per row (b,n). Coordinates (+|c|^2) staged
// in LDS as float4; distances recomputed in fp32; any candidate within
// BAND=1e-4 of the threshold falls back to the EXACT precomputed matrix
// element, so classification matches the reference bit-for-bit.
__global__ __launch_bounds__(256, 2) void k2_ball(
    const float* __restrict__ coords, const float* __restrict__ DM,
    int* __restrict__ idx_buf)
{
    __shared__ float4 sc[NN];  // 64 KB: x,y,z,|c|^2 per point of this batch
    const int lane = threadIdx.x & 63;
    const int w = threadIdx.x >> 6;
    const int row = blockIdx.x * 4 + w;   // b*N + n  (4 | N so b uniform/block)
    const int b = row >> 12;
    const int n = row & (NN - 1);
    const float* cb = coords + (size_t)b * NN * 3;
    for (int i = threadIdx.x; i < NN; i += 256) {
        float x = cb[3 * i], y = cb[3 * i + 1], z = cb[3 * i + 2];
        sc[i] = make_float4(x, y, z, fmaf(z, z, fmaf(y, y, x * x)));
    }
    __syncthreads();

    const float4 pn = sc[n];
    const float sqn = pn.w;
    // IMPORTANT: JAX promotes the weak python scalar 0.1*0.1 (double) to f32:
    // (float)(0.01000000000000000208) = 0x3C23D70A. 0.1f*0.1f would be 1 ulp high.
    const float R2 = (float)(0.1 * 0.1);
    const float BAND = 1e-4f;
    const float* dmrow = DM + (size_t)row * NN;
    int* out = idx_buf + (size_t)row * KNB;

    int cnt = 0, first = n;
    for (int mb = 0; mb < NN; mb += 64) {
        const int mm = mb + lane;
        float4 pm = sc[mm];
        float dot = fmaf(pn.z, pm.z, fmaf(pn.y, pm.y, pn.x * pm.x));
        float dd = fmaf(-2.0f, dot, sqn + pm.w);
        bool within;
        if (fabsf(dd - R2) <= BAND)
            within = (dmrow[mm] <= R2);   // rare exact fallback
        else
            within = (dd <= R2);          // (clamp-to-0 irrelevant: neg <= R2 anyway)
        unsigned long long msk = __ballot(within);
        if (msk) {
            if (within) {
                int pos = cnt + __popcll(msk & ((1ull << lane) - 1ull));
                if (pos < KNB) out[pos] = mm;
            }
            if (cnt == 0) first = mb + (int)__builtin_ctzll(msk);
            cnt += __popcll(msk);
            if (cnt >= KNB) break;        // cnt uniform (ballot) -> uniform break
        }
    }
    // pad slots [cnt, K) with the first in-ball index (reference semantics)
    if (lane >= cnt && lane < KNB) out[lane] = first;
}

// Kernel 3: per point p (one wave): for each of K neighbors,
//   v = a[idx_k] + c[n];  LN via (Sa_k+Sc)/64 mean and one wave-reduce of v^2;
//   out = max_k relu(LN(v)*g2+be2).  Two k's in flight to hide shuffle latency.
__global__ __launch_bounds__(256, 4) void k3_out(
    const float* __restrict__ a_buf, const float* __restrict__ c_buf,
    const float* __restrict__ Sa_buf, const int* __restrict__ idx_buf,
    const float* __restrict__ g2, const float* __restrict__ be2,
    float* __restrict__ outp)
{
    const int lane = threadIdx.x & 63;
    const int p = (blockIdx.x * 256 + threadIdx.x) >> 6;
    const int b = p >> 12;
    const float* abase = a_buf + ((size_t)(b << 12)) * DIMS;
    const float cv = c_buf[(size_t)p * DIMS + lane];
    const float Sc = wsum64(cv);
    int myi = 0; float mySa = 0.0f;
    if (lane < KNB) {
        myi = idx_buf[(size_t)p * KNB + lane];
        mySa = Sa_buf[(b << 12) + myi];
    }
    const float gg = g2[lane], bb = be2[lane];
    float om0 = 0.0f, om1 = 0.0f;  // y >= 0 after relu, so 0-init == -inf-init
#pragma unroll 4
    for (int k = 0; k < KNB; k += 2) {
        int m0 = __shfl(myi, k, 64);
        int m1 = __shfl(myi, k + 1, 64);
        float Sa0 = __shfl(mySa, k, 64);
        float Sa1 = __shfl(mySa, k + 1, 64);
        float v0 = abase[(size_t)m0 * DIMS + lane] + cv;
        float v1 = abase[(size_t)m1 * DIMS + lane] + cv;
        float q0 = v0 * v0, q1 = v1 * v1;
#pragma unroll
        for (int off = 32; off > 0; off >>= 1) {
            q0 += __shfl_xor(q0, off, 64);
            q1 += __shfl_xor(q1, off, 64);
        }
        float mu0 = (Sa0 + Sc) * (1.0f / DIMS);
        float mu1 = (Sa1 + Sc) * (1.0f / DIMS);
        float var0 = q0 * (1.0f / DIMS) - mu0 * mu0;
        float var1 = q1 * (1.0f / DIMS) - mu1 * mu1;
        float y0 = (v0 - mu0) * rsqrtf(var0 + LN_EPS) * gg + bb;
        float y1 = (v1 - mu1) * rsqrtf(var1 + LN_EPS) * gg + bb;
        om0 = fmaxf(om0, y0);
        om1 = fmaxf(om1, y1);
    }
    outp[(size_t)p * DIMS + lane] = fmaxf(fmaxf(om0, om1), 0.0f);
}

extern "C" void kernel_launch(void* const* d_in, const int* in_sizes, int n_in,
                              void* d_out, int out_size, void* d_ws, size_t ws_size,
                              hipStream_t stream)
{
    const float* inp    = (const float*)d_in[0];
    const float* coords = (const float*)d_in[1];
    const float* DM     = (const float*)d_in[2];
    const float* W1     = (const float*)d_in[3];
    const float* b1     = (const float*)d_in[4];
    const float* g1     = (const float*)d_in[5];
    const float* be1    = (const float*)d_in[6];
    const float* W2     = (const float*)d_in[7];
    const float* b2     = (const float*)d_in[8];
    const float* g2     = (const float*)d_in[9];
    const float* be2    = (const float*)d_in[10];
    float* out = (float*)d_out;

    char* ws = (char*)d_ws;
    float* a_buf  = (float*)ws;                                        // 8 MB
    float* c_buf  = (float*)(ws + (size_t)BN * DIMS * 4);              // 8 MB
    int*   idx_buf = (int*)(ws + (size_t)2 * BN * DIMS * 4);           // 4 MB
    float* Sa_buf = (float*)(ws + (size_t)2 * BN * DIMS * 4
                                + (size_t)BN * KNB * 4);               // 128 KB

    dim3 blk(256);
    dim3 grd(BN / 4);  // 4 waves/block, 1 point or row per wave
    k1_feat<<<grd, blk, 0, stream>>>(inp, W1, b1, g1, be1, W2, b2,
                                     a_buf, c_buf, Sa_buf);
    k2_ball<<<grd, blk, 0, stream>>>(coords, DM, idx_buf);
    k3_out<<<grd, blk, 0, stream>>>(a_buf, c_buf, Sa_buf, idx_buf, g2, be2, out);
}

// Round 3
// 770.523 us; speedup vs baseline: 1.1524x; 1.1524x over previous
//
#include <hip/hip_runtime.h>
#include <cstdint>
#include <cstddef>

#define BB 8
#define NN 4096
#define IDIM 6
#define DIMS 64
#define KNB 32
#define BN (BB * NN)

static constexpr float LN_EPS = 1e-5f;

// ---- wave-64 sum with minimal LDS-pipe use:
// xor1/xor2 via DPP quad_perm, xor8 via DPP row_ror:8 (pure VALU),
// xor4/xor16 via ds_swizzle, xor32 via one bpermute (__shfl_xor).
// (builtins need LITERAL ctrl operands -> template params)
template<int CTRL>
__device__ __forceinline__ float dpp_xadd(float v) {
    int r = __builtin_amdgcn_update_dpp(0, __float_as_int(v), CTRL, 0xF, 0xF, true);
    return v + __int_as_float(r);
}
template<int OFFS>
__device__ __forceinline__ float swz_xadd(float v) {
    int r = __builtin_amdgcn_ds_swizzle(__float_as_int(v), OFFS);
    return v + __int_as_float(r);
}
__device__ __forceinline__ float wsum64(float v) {
    v = dpp_xadd<0xB1>(v);       // xor 1  (quad_perm [1,0,3,2])
    v = dpp_xadd<0x4E>(v);       // xor 2  (quad_perm [2,3,0,1])
    v = swz_xadd<0x101F>(v);     // xor 4  (ds_swizzle bitmode, per 32-lane half)
    v = dpp_xadd<0x128>(v);      // xor 8  (row_ror:8 == xor8 within 16-lane row)
    v = swz_xadd<0x401F>(v);     // xor 16
    v += __shfl_xor(v, 32, 64);  // xor 32 (crosses the 32-lane halves)
    return v;
}

// Kernel 1: per point p (one wave = 64 dims):
//   x  = relu(LN(inputs@W1 + b1))
//   a  = x @ W2[0:64]            (gatherable neighbor part)
//   c  = x @ W2[64:128] + b2 - a (per-center constant part)
//   Sa = sum_d a[d]              (free LN means downstream)
// plus packs cq[p] = (x,y,z,|c|^2) for the ball-query kernel.
__global__ __launch_bounds__(256, 4) void k1_feat(
    const float* __restrict__ inp, const float* __restrict__ coords,
    const float* __restrict__ W1, const float* __restrict__ b1,
    const float* __restrict__ g1, const float* __restrict__ be1,
    const float* __restrict__ W2, const float* __restrict__ b2,
    float* __restrict__ a_buf, float* __restrict__ c_buf,
    float* __restrict__ Sa_buf, float4* __restrict__ cq_buf)
{
    const int lane = threadIdx.x & 63;
    const int p = (blockIdx.x << 2) + (threadIdx.x >> 6);

    if (threadIdx.x < 4) {  // pack this block's 4 points
        const int pp = (blockIdx.x << 2) + threadIdx.x;
        const float x = coords[3 * pp], y = coords[3 * pp + 1], z = coords[3 * pp + 2];
        cq_buf[pp] = make_float4(x, y, z, fmaf(z, z, fmaf(y, y, x * x)));
    }

    const float* ip = inp + (size_t)p * IDIM;
    float h = b1[lane];
#pragma unroll
    for (int j = 0; j < IDIM; ++j)
        h = fmaf(ip[j], W1[j * DIMS + lane], h);
    const float mean = wsum64(h) * (1.0f / DIMS);
    const float dv = h - mean;
    const float var = wsum64(dv * dv) * (1.0f / DIMS);
    const float x = fmaxf(dv * rsqrtf(var + LN_EPS) * g1[lane] + be1[lane], 0.0f);

    float a = 0.0f, cp = 0.0f;
    const int xi = __float_as_int(x);
#pragma unroll 8
    for (int j = 0; j < DIMS; ++j) {
        const int sj = __builtin_amdgcn_readlane(xi, j);  // uniform broadcast, no LDS
        if (sj != 0) {  // relu zeros (+0 only) -> uniform skip of loads+FMAs
            const float xj = __int_as_float(sj);
            a  = fmaf(xj, W2[j * DIMS + lane], a);
            cp = fmaf(xj, W2[(DIMS + j) * DIMS + lane], cp);
        }
    }
    const float c = cp + b2[lane] - a;
    a_buf[(size_t)p * DIMS + lane] = a;
    c_buf[(size_t)p * DIMS + lane] = c;
    const float sa = wsum64(a);
    if (lane == 0) Sa_buf[p] = sa;
}

// Kernel 2+3 fused: one wave per row (b,n).
// Phase A: ball query against LDS-staged cq; neighbor indices assigned to
//          owner lanes via scalar ctz-loop over the ballot mask (registers only).
//          Recomputed distance, exact-DM fallback inside +-1e-4 band => bitwise
//          classification match with the reference.
// Phase B: v = a[m_k] + c[n]; mean from Sa[m]+Sc (precomputed); two-pass LN
//          (d = v - mu before squaring); max over k. 4-way ILP.
__global__ __launch_bounds__(512, 4) void k23(
    const float4* __restrict__ cq, const float* __restrict__ DM,
    const float* __restrict__ a_buf, const float* __restrict__ c_buf,
    const float* __restrict__ Sa_buf, const float* __restrict__ g2,
    const float* __restrict__ be2, float* __restrict__ outp)
{
    __shared__ float4 sc[NN];  // 64 KB

    // XCD-aware swizzle: 4096 blocks, 8 XCDs -> XCD x gets one contiguous
    // 512-block chunk == exactly one batch => its L2 holds that batch's
    // a (1MB) + Sa + cq hot.
    const int bid = ((blockIdx.x & 7) << 9) + (blockIdx.x >> 3);
    const int lane = threadIdx.x & 63;
    const int w = threadIdx.x >> 6;       // 0..7
    const int row = (bid << 3) + w;       // b*N + n
    const int b = row >> 12;
    const int n = row & (NN - 1);

    const float4* cb = cq + ((size_t)b << 12);
    for (int i = threadIdx.x; i < NN; i += 512)
        sc[i] = cb[i];
    __syncthreads();

    const float4 pn = sc[n];
    // JAX promotes the weak scalar 0.1*0.1 (double) then casts to f32:
    // 0x3C23D70A. (0.1f*0.1f would be 1 ulp high.)
    const float R2 = (float)(0.1 * 0.1);
    const float thr = R2 - pn.w;          // e = pm.w - 2*dot <= thr  <=>  within
    const float BAND = 1e-4f;
    const float* __restrict__ dmrow = DM + (size_t)row * NN;

    int cnt = 0, first = n, myidx = 0;
    for (int mb = 0; mb < NN; mb += 64) {
        const int mm = mb + lane;
        const float4 pm = sc[mm];
        const float dot = fmaf(pn.z, pm.z, fmaf(pn.y, pm.y, pn.x * pm.x));
        const float e = fmaf(-2.0f, dot, pm.w);
        bool within = (e <= thr);
        const bool band = fabsf(e - thr) <= BAND;
        if (__any(band)) {                 // rare (~0.8% of iterations)
            if (band) within = (dmrow[mm] <= R2);  // exact classification
        }
        unsigned long long msk = __ballot(within);
        if (msk) {
            if (cnt == 0) first = mb + (int)__builtin_ctzll(msk);
            while (msk && cnt < KNB) {     // assign set bits to lanes cnt..
                const int t = (int)__builtin_ctzll(msk);
                if (lane == cnt) myidx = mb + t;
                msk &= msk - 1;
                ++cnt;
            }
            if (cnt >= KNB) break;         // uniform
        }
    }
    if (lane >= cnt && lane < KNB) myidx = first;  // reference pad semantics

    // ---------------- Phase B ----------------
    const float cv = c_buf[(size_t)row * DIMS + lane];
    const float Sc = wsum64(cv);
    const float gg = g2[lane], bb = be2[lane];
    const float* __restrict__ abase = a_buf + (((size_t)b << 12) * DIMS);
    const float* __restrict__ Sab = Sa_buf + (b << 12);
    const int mix = myidx;

    float om0 = 0.0f, om1 = 0.0f, om2 = 0.0f, om3 = 0.0f;
#pragma unroll 2
    for (int k = 0; k < KNB; k += 4) {
        const int m0 = __builtin_amdgcn_readlane(mix, k + 0);  // uniform (SGPR)
        const int m1 = __builtin_amdgcn_readlane(mix, k + 1);
        const int m2 = __builtin_amdgcn_readlane(mix, k + 2);
        const int m3 = __builtin_amdgcn_readlane(mix, k + 3);
        const float mu0 = (Sab[m0] + Sc) * (1.0f / DIMS);      // scalar loads
        const float mu1 = (Sab[m1] + Sc) * (1.0f / DIMS);
        const float mu2 = (Sab[m2] + Sc) * (1.0f / DIMS);
        const float mu3 = (Sab[m3] + Sc) * (1.0f / DIMS);
        const float d0 = abase[(size_t)m0 * DIMS + lane] + cv - mu0;
        const float d1 = abase[(size_t)m1 * DIMS + lane] + cv - mu1;
        const float d2 = abase[(size_t)m2 * DIMS + lane] + cv - mu2;
        const float d3 = abase[(size_t)m3 * DIMS + lane] + cv - mu3;
        const float q0 = wsum64(d0 * d0);
        const float q1 = wsum64(d1 * d1);
        const float q2 = wsum64(d2 * d2);
        const float q3 = wsum64(d3 * d3);
        const float y0 = d0 * rsqrtf(q0 * (1.0f / DIMS) + LN_EPS) * gg + bb;
        const float y1 = d1 * rsqrtf(q1 * (1.0f / DIMS) + LN_EPS) * gg + bb;
        const float y2 = d2 * rsqrtf(q2 * (1.0f / DIMS) + LN_EPS) * gg + bb;
        const float y3 = d3 * rsqrtf(q3 * (1.0f / DIMS) + LN_EPS) * gg + bb;
        om0 = fmaxf(om0, y0);
        om1 = fmaxf(om1, y1);
        om2 = fmaxf(om2, y2);
        om3 = fmaxf(om3, y3);
    }
    outp[(size_t)row * DIMS + lane] =
        fmaxf(fmaxf(fmaxf(om0, om1), fmaxf(om2, om3)), 0.0f);
}

extern "C" void kernel_launch(void* const* d_in, const int* in_sizes, int n_in,
                              void* d_out, int out_size, void* d_ws, size_t ws_size,
                              hipStream_t stream)
{
    const float* inp    = (const float*)d_in[0];
    const float* coords = (const float*)d_in[1];
    const float* DM     = (const float*)d_in[2];
    const float* W1     = (const float*)d_in[3];
    const float* b1v    = (const float*)d_in[4];
    const float* g1     = (const float*)d_in[5];
    const float* be1    = (const float*)d_in[6];
    const float* W2     = (const float*)d_in[7];
    const float* b2v    = (const float*)d_in[8];
    const float* g2     = (const float*)d_in[9];
    const float* be2    = (const float*)d_in[10];
    float* out = (float*)d_out;

    char* ws = (char*)d_ws;
    float*  a_buf  = (float*)(ws);                                   // 8 MB
    float*  c_buf  = (float*)(ws + (size_t)BN * DIMS * 4);           // 8 MB
    float*  Sa_buf = (float*)(ws + (size_t)2 * BN * DIMS * 4);       // 128 KB
    float4* cq     = (float4*)(ws + (size_t)2 * BN * DIMS * 4
                                  + (size_t)BN * 4);                 // 512 KB

    k1_feat<<<dim3(BN / 4), dim3(256), 0, stream>>>(
        inp, coords, W1, b1v, g1, be1, W2, b2v, a_buf, c_buf, Sa_buf, cq);
    k23<<<dim3(BN / 8), dim3(512), 0, stream>>>(
        cq, DM, a_buf, c_buf, Sa_buf, g2, be2, out);
}

// Round 5
// 685.811 us; speedup vs baseline: 1.2948x; 1.1235x over previous
//
#include <hip/hip_runtime.h>
#include <cstdint>
#include <cstddef>

#define BB 8
#define NN 4096
#define IDIM 6
#define DIMS 64
#define KNB 32
#define BN (BB * NN)
#define NCELL 1024  // 10x10x10 cells, padded to 1024 per batch

static constexpr float LN_EPS = 1e-5f;
static constexpr float INV_SIDE = 1.0f / 0.11f;  // cell side 0.11 > radius 0.1 (safe +-1 window)

// ---- wave-64 sum: xor1/2 DPP quad_perm, xor8 DPP row_ror:8, xor4/16 ds_swizzle,
// xor32 bpermute. Builtins need LITERAL ctrl -> template params.
template<int CTRL>
__device__ __forceinline__ float dpp_xadd(float v) {
    int r = __builtin_amdgcn_update_dpp(0, __float_as_int(v), CTRL, 0xF, 0xF, true);
    return v + __int_as_float(r);
}
template<int OFFS>
__device__ __forceinline__ float swz_xadd(float v) {
    int r = __builtin_amdgcn_ds_swizzle(__float_as_int(v), OFFS);
    return v + __int_as_float(r);
}
__device__ __forceinline__ float wsum64(float v) {
    v = dpp_xadd<0xB1>(v);
    v = dpp_xadd<0x4E>(v);
    v = swz_xadd<0x101F>(v);
    v = dpp_xadd<0x128>(v);
    v = swz_xadd<0x401F>(v);
    v += __shfl_xor(v, 32, 64);
    return v;
}

// ---- in-wave bitonic sort (64 lanes, ascending)
template<int K, int J>
__device__ __forceinline__ void bstep(int& v, int lane) {
    const int o = __shfl_xor(v, J, 64);
    const bool up = (lane & K) == 0;
    const bool lower = (lane & J) == 0;
    v = (lower == up) ? min(v, o) : max(v, o);
}
__device__ __forceinline__ void sort64(int& v, int lane) {
    bstep<2,1>(v,lane);
    bstep<4,2>(v,lane);  bstep<4,1>(v,lane);
    bstep<8,4>(v,lane);  bstep<8,2>(v,lane);  bstep<8,1>(v,lane);
    bstep<16,8>(v,lane); bstep<16,4>(v,lane); bstep<16,2>(v,lane); bstep<16,1>(v,lane);
    bstep<32,16>(v,lane); bstep<32,8>(v,lane); bstep<32,4>(v,lane); bstep<32,2>(v,lane); bstep<32,1>(v,lane);
    bstep<64,32>(v,lane); bstep<64,16>(v,lane); bstep<64,8>(v,lane); bstep<64,4>(v,lane); bstep<64,2>(v,lane); bstep<64,1>(v,lane);
}

__device__ __forceinline__ int cell_of(float x, float y, float z) {
    const int cx = min((int)(x * INV_SIDE), 9);
    const int cy = min((int)(y * INV_SIDE), 9);
    const int cz = min((int)(z * INV_SIDE), 9);
    return cx * 100 + cy * 10 + cz;
}

// ---- CSR build over 10^3 cells (side 0.11) + cq packing
__global__ __launch_bounds__(256) void k_count(const float* __restrict__ coords,
                                               int* __restrict__ counts,
                                               float4* __restrict__ cq)
{
    const int p = blockIdx.x * 256 + threadIdx.x;
    const float x = coords[3 * p], y = coords[3 * p + 1], z = coords[3 * p + 2];
    cq[p] = make_float4(x, y, z, fmaf(z, z, fmaf(y, y, x * x)));
    const int b = p >> 12;
    atomicAdd(&counts[(b << 10) + cell_of(x, y, z)], 1);
}

__global__ __launch_bounds__(256) void k_scan(const int* __restrict__ counts,
                                              int* __restrict__ starts,
                                              int* __restrict__ cursor)
{
    __shared__ int ssum[256];
    const int b = blockIdx.x, t = threadIdx.x;
    const int base = (b << 10) + (t << 2);
    const int c0 = counts[base], c1 = counts[base + 1];
    const int c2 = counts[base + 2], c3 = counts[base + 3];
    const int s = c0 + c1 + c2 + c3;
    ssum[t] = s;
    __syncthreads();
    int acc = s;
    for (int off = 1; off < 256; off <<= 1) {  // Hillis-Steele inclusive
        const int v = (t >= off) ? ssum[t - off] : 0;
        __syncthreads();
        acc += v; ssum[t] = acc;
        __syncthreads();
    }
    int run = acc - s;  // exclusive prefix of this thread's 4 cells
    starts[base] = run; cursor[base] = run; run += c0;
    starts[base + 1] = run; cursor[base + 1] = run; run += c1;
    starts[base + 2] = run; cursor[base + 2] = run; run += c2;
    starts[base + 3] = run; cursor[base + 3] = run;
}

__global__ __launch_bounds__(256) void k_scatter(const float* __restrict__ coords,
                                                 int* __restrict__ cursor,
                                                 int* __restrict__ csr)
{
    const int p = blockIdx.x * 256 + threadIdx.x;
    const float x = coords[3 * p], y = coords[3 * p + 1], z = coords[3 * p + 2];
    const int b = p >> 12;
    const int pos = atomicAdd(&cursor[(b << 10) + cell_of(x, y, z)], 1);
    csr[(b << 12) + pos] = p & (NN - 1);
}

// ---- k1: x = relu(LN(inp@W1+b1)); a = x@W2[0:64]; c = x@W2[64:128]+b2-a; Sa = sum(a)
__global__ __launch_bounds__(256, 4) void k1_feat(
    const float* __restrict__ inp, const float* __restrict__ W1,
    const float* __restrict__ b1, const float* __restrict__ g1,
    const float* __restrict__ be1, const float* __restrict__ W2,
    const float* __restrict__ b2,
    float* __restrict__ a_buf, float* __restrict__ c_buf,
    float* __restrict__ Sa_buf)
{
    const int lane = threadIdx.x & 63;
    const int p = (blockIdx.x << 2) + (threadIdx.x >> 6);
    const float* ip = inp + (size_t)p * IDIM;
    float h = b1[lane];
#pragma unroll
    for (int j = 0; j < IDIM; ++j)
        h = fmaf(ip[j], W1[j * DIMS + lane], h);
    const float mean = wsum64(h) * (1.0f / DIMS);
    const float dv = h - mean;
    const float var = wsum64(dv * dv) * (1.0f / DIMS);
    const float x = fmaxf(dv * rsqrtf(var + LN_EPS) * g1[lane] + be1[lane], 0.0f);

    float a = 0.0f, cp = 0.0f;
    const int xi = __float_as_int(x);
#pragma unroll 8
    for (int j = 0; j < DIMS; ++j) {
        const int sj = __builtin_amdgcn_readlane(xi, j);
        if (sj != 0) {  // relu zeros -> uniform skip
            const float xj = __int_as_float(sj);
            a  = fmaf(xj, W2[j * DIMS + lane], a);
            cp = fmaf(xj, W2[(DIMS + j) * DIMS + lane], cp);
        }
    }
    const float c = cp + b2[lane] - a;
    a_buf[(size_t)p * DIMS + lane] = a;
    c_buf[(size_t)p * DIMS + lane] = c;
    const float sa = wsum64(a);
    if (lane == 0) Sa_buf[p] = sa;
}

// ---- k23: binned ball query + gather-LN-max. One wave per row.
__global__ __launch_bounds__(512, 4) void k23(
    const float4* __restrict__ cq, const float* __restrict__ DM,
    const float* __restrict__ a_buf, const float* __restrict__ c_buf,
    const float* __restrict__ Sa_buf, const int* __restrict__ starts,
    const int* __restrict__ counts, const int* __restrict__ csr,
    const float* __restrict__ g2, const float* __restrict__ be2,
    float* __restrict__ outp)
{
    __shared__ int p_tab[8][32];  // exclusive candidate-prefix per neighbor cell
    __shared__ int s_tab[8][32];  // csr start per neighbor cell
    __shared__ int hits[8][64];   // collected in-ball indices (unsorted)

    // XCD swizzle: 4096 blocks -> each XCD owns one batch (512 contiguous bids)
    const int bid = ((blockIdx.x & 7) << 9) + (blockIdx.x >> 3);
    const int lane = threadIdx.x & 63;
    const int w = threadIdx.x >> 6;
    const int row = (bid << 3) + w;
    const int b = row >> 12;
    const int n = row & (NN - 1);

    const float4* __restrict__ cqb = cq + ((size_t)b << 12);
    const float4 pn = cqb[n];
    // JAX weak-scalar promotion: (float)(0.1*0.1) = 0x3C23D70A, not 0.1f*0.1f.
    const float R2 = (float)(0.1 * 0.1);
    const float thr = R2 - pn.w;  // e = pm.w - 2*dot <= thr  <=>  within
    const float BAND = 1e-4f;     // recompute err <= ~3e-6 -> exact-DM fallback band
    const float* __restrict__ dmrow = DM + (size_t)row * NN;

    const int cx = min((int)(pn.x * INV_SIDE), 9);
    const int cy = min((int)(pn.y * INV_SIDE), 9);
    const int cz = min((int)(pn.z * INV_SIDE), 9);

    int cnt_i = 0, start_i = 0;
    if (lane < 27) {
        const int dx = lane / 9 - 1, dy = (lane / 3) % 3 - 1, dz = lane % 3 - 1;
        const int X = cx + dx, Y = cy + dy, Z = cz + dz;
        if ((unsigned)X <= 9u && (unsigned)Y <= 9u && (unsigned)Z <= 9u) {
            const int cid = (b << 10) + X * 100 + Y * 10 + Z;
            cnt_i = counts[cid];
            start_i = starts[cid];
        }
    }
    int incl = cnt_i;  // inclusive lane-scan of candidate counts
#pragma unroll
    for (int s = 1; s < 64; s <<= 1) {
        const int tv = __shfl_up(incl, s, 64);
        if (lane >= s) incl += tv;
    }
    const int T = __builtin_amdgcn_readlane(incl, 63);  // total candidates (~150)
    if (lane < 32) {
        p_tab[w][lane] = (lane < 27) ? (incl - cnt_i) : T;
        s_tab[w][lane] = start_i;
    }
    __syncthreads();

    int cnt = 0;
    for (int tb = 0; tb < T; tb += 64) {
        const int t = tb + lane;
        int mm = 0;
        bool within = false;
        if (t < T) {
            int c = 0;  // last cell with prefix <= t (5-step search over 32 entries)
#pragma unroll
            for (int s = 16; s >= 1; s >>= 1)
                if (p_tab[w][c + s] <= t) c += s;
            const int j = t - p_tab[w][c];
            mm = csr[(b << 12) + s_tab[w][c] + j];
            const float4 pm = cqb[mm];
            const float dot = fmaf(pn.z, pm.z, fmaf(pn.y, pm.y, pn.x * pm.x));
            const float e = fmaf(-2.0f, dot, pm.w);
            within = (e <= thr);
            if (fabsf(e - thr) <= BAND) within = (dmrow[mm] <= R2);  // exact
        }
        const unsigned long long msk = __ballot(within);
        if (within) {
            const int pos = cnt + __popcll(msk & ((1ull << lane) - 1ull));
            if (pos < 64) hits[w][pos] = mm;
        }
        cnt += __popcll(msk);
    }
    __syncthreads();

    int myidx = 0x7fffffff;
    if (cnt <= 64) {
        if (lane < cnt) myidx = hits[w][lane];
    } else {
        // overflow fallback (p ~ 0): exact ordered full scan, first 32
        cnt = 0;
        for (int mb = 0; mb < NN && cnt < KNB; mb += 64) {
            const int mmf = mb + lane;
            const float4 pm = cqb[mmf];
            const float dot = fmaf(pn.z, pm.z, fmaf(pn.y, pm.y, pn.x * pm.x));
            const float e = fmaf(-2.0f, dot, pm.w);
            bool wi = (e <= thr);
            if (fabsf(e - thr) <= BAND) wi = (dmrow[mmf] <= R2);
            unsigned long long m2 = __ballot(wi);
            while (m2 && cnt < KNB) {
                const int src = (int)__builtin_ctzll(m2);
                if (lane == cnt) myidx = mb + src;
                m2 &= m2 - 1;
                ++cnt;
            }
        }
    }
    sort64(myidx, lane);               // ascending; sentinels go high
    const int KK = min(cnt, KNB);      // members only; padding can't change a max

    // ---------------- Phase B ----------------
    const float cv = c_buf[(size_t)row * DIMS + lane];
    const float Sc = wsum64(cv);
    const float gg = g2[lane], bb = be2[lane];
    const float* __restrict__ abase = a_buf + ((size_t)(b << 12) * DIMS);
    const float* __restrict__ Sab = Sa_buf + (b << 12);
    const int mix = myidx;

    float om0 = 0.0f, om1 = 0.0f, om2 = 0.0f, om3 = 0.0f;
    for (int k = 0; k < KK; k += 4) {
        const int ka = min(k + 1, KK - 1);  // dup of a member: max unchanged
        const int kb2 = min(k + 2, KK - 1);
        const int kc = min(k + 3, KK - 1);
        const int m0 = __builtin_amdgcn_readlane(mix, k);
        const int m1 = __builtin_amdgcn_readlane(mix, ka);
        const int m2 = __builtin_amdgcn_readlane(mix, kb2);
        const int m3 = __builtin_amdgcn_readlane(mix, kc);
        const float mu0 = (Sab[m0] + Sc) * (1.0f / DIMS);
        const float mu1 = (Sab[m1] + Sc) * (1.0f / DIMS);
        const float mu2 = (Sab[m2] + Sc) * (1.0f / DIMS);
        const float mu3 = (Sab[m3] + Sc) * (1.0f / DIMS);
        const float d0 = abase[(size_t)m0 * DIMS + lane] + cv - mu0;
        const float d1 = abase[(size_t)m1 * DIMS + lane] + cv - mu1;
        const float d2 = abase[(size_t)m2 * DIMS + lane] + cv - mu2;
        const float d3 = abase[(size_t)m3 * DIMS + lane] + cv - mu3;
        const float q0 = wsum64(d0 * d0);
        const float q1 = wsum64(d1 * d1);
        const float q2 = wsum64(d2 * d2);
        const float q3 = wsum64(d3 * d3);
        const float y0 = d0 * rsqrtf(q0 * (1.0f / DIMS) + LN_EPS) * gg + bb;
        const float y1 = d1 * rsqrtf(q1 * (1.0f / DIMS) + LN_EPS) * gg + bb;
        const float y2 = d2 * rsqrtf(q2 * (1.0f / DIMS) + LN_EPS) * gg + bb;
        const float y3 = d3 * rsqrtf(q3 * (1.0f / DIMS) + LN_EPS) * gg + bb;
        om0 = fmaxf(om0, y0);
        om1 = fmaxf(om1, y1);
        om2 = fmaxf(om2, y2);
        om3 = fmaxf(om3, y3);
    }
    outp[(size_t)row * DIMS + lane] =
        fmaxf(fmaxf(fmaxf(om0, om1), fmaxf(om2, om3)), 0.0f);
}

extern "C" void kernel_launch(void* const* d_in, const int* in_sizes, int n_in,
                              void* d_out, int out_size, void* d_ws, size_t ws_size,
                              hipStream_t stream)
{
    const float* inp    = (const float*)d_in[0];
    const float* coords = (const float*)d_in[1];
    const float* DM     = (const float*)d_in[2];
    const float* W1     = (const float*)d_in[3];
    const float* b1v    = (const float*)d_in[4];
    const float* g1     = (const float*)d_in[5];
    const float* be1    = (const float*)d_in[6];
    const float* W2     = (const float*)d_in[7];
    const float* b2v    = (const float*)d_in[8];
    const float* g2     = (const float*)d_in[9];
    const float* be2    = (const float*)d_in[10];
    float* out = (float*)d_out;

    char* ws = (char*)d_ws;
    size_t off = 0;
    float*  a_buf  = (float*)(ws + off); off += (size_t)BN * DIMS * 4;   // 8 MB
    float*  c_buf  = (float*)(ws + off); off += (size_t)BN * DIMS * 4;   // 8 MB
    float*  Sa_buf = (float*)(ws + off); off += (size_t)BN * 4;          // 128 KB
    float4* cq     = (float4*)(ws + off); off += (size_t)BN * 16;        // 512 KB
    int*    counts = (int*)(ws + off); off += (size_t)BB * NCELL * 4;    // 32 KB
    int*    starts = (int*)(ws + off); off += (size_t)BB * NCELL * 4;    // 32 KB
    int*    cursor = (int*)(ws + off); off += (size_t)BB * NCELL * 4;    // 32 KB
    int*    csr    = (int*)(ws + off); off += (size_t)BN * 4;            // 128 KB

    hipMemsetAsync(counts, 0, (size_t)BB * NCELL * 4, stream);
    k_count<<<dim3(BN / 256), dim3(256), 0, stream>>>(coords, counts, cq);
    k_scan<<<dim3(BB), dim3(256), 0, stream>>>(counts, starts, cursor);
    k_scatter<<<dim3(BN / 256), dim3(256), 0, stream>>>(coords, cursor, csr);
    k1_feat<<<dim3(BN / 4), dim3(256), 0, stream>>>(
        inp, W1, b1v, g1, be1, W2, b2v, a_buf, c_buf, Sa_buf);
    k23<<<dim3(BN / 8), dim3(512), 0, stream>>>(
        cq, DM, a_buf, c_buf, Sa_buf, starts, counts, csr, g2, be2, out);
}

// Round 6
// 673.408 us; speedup vs baseline: 1.3186x; 1.0184x over previous
//
#include <hip/hip_runtime.h>
#include <cstdint>
#include <cstddef>

#define BB 8
#define NN 4096
#define IDIM 6
#define DIMS 64
#define KNB 32
#define BN (BB * NN)
#define NCELL 1024  // 10x10x10 cells, padded to 1024 per batch

static constexpr float LN_EPS = 1e-5f;
static constexpr float INV_SIDE = 1.0f / 0.11f;  // cell side 0.11 > radius 0.1 (safe +-1 window)

// ---- wave-64 sum: xor1/2 DPP quad_perm, xor8 DPP row_ror:8, xor4/16 ds_swizzle,
// xor32 bpermute. Builtins need LITERAL ctrl -> template params.
template<int CTRL>
__device__ __forceinline__ float dpp_xadd(float v) {
    int r = __builtin_amdgcn_update_dpp(0, __float_as_int(v), CTRL, 0xF, 0xF, true);
    return v + __int_as_float(r);
}
template<int OFFS>
__device__ __forceinline__ float swz_xadd(float v) {
    int r = __builtin_amdgcn_ds_swizzle(__float_as_int(v), OFFS);
    return v + __int_as_float(r);
}
__device__ __forceinline__ float wsum64(float v) {
    v = dpp_xadd<0xB1>(v);
    v = dpp_xadd<0x4E>(v);
    v = swz_xadd<0x101F>(v);
    v = dpp_xadd<0x128>(v);
    v = swz_xadd<0x401F>(v);
    v += __shfl_xor(v, 32, 64);
    return v;
}

// ---- in-wave bitonic sort (64 lanes, ascending)
template<int K, int J>
__device__ __forceinline__ void bstep(int& v, int lane) {
    const int o = __shfl_xor(v, J, 64);
    const bool up = (lane & K) == 0;
    const bool lower = (lane & J) == 0;
    v = (lower == up) ? min(v, o) : max(v, o);
}
__device__ __forceinline__ void sort64(int& v, int lane) {
    bstep<2,1>(v,lane);
    bstep<4,2>(v,lane);  bstep<4,1>(v,lane);
    bstep<8,4>(v,lane);  bstep<8,2>(v,lane);  bstep<8,1>(v,lane);
    bstep<16,8>(v,lane); bstep<16,4>(v,lane); bstep<16,2>(v,lane); bstep<16,1>(v,lane);
    bstep<32,16>(v,lane); bstep<32,8>(v,lane); bstep<32,4>(v,lane); bstep<32,2>(v,lane); bstep<32,1>(v,lane);
    bstep<64,32>(v,lane); bstep<64,16>(v,lane); bstep<64,8>(v,lane); bstep<64,4>(v,lane); bstep<64,2>(v,lane); bstep<64,1>(v,lane);
}

__device__ __forceinline__ int cell_of(float x, float y, float z) {
    const int cx = min((int)(x * INV_SIDE), 9);
    const int cy = min((int)(y * INV_SIDE), 9);
    const int cz = min((int)(z * INV_SIDE), 9);
    return cx * 100 + cy * 10 + cz;
}

// ---- Merged CSR build: one block (1024 thr) per batch. LDS counts ->
// Hillis-Steele scan over 1024 cells -> LDS-cursor scatter. Also packs cq.
__global__ __launch_bounds__(1024) void k_csr(const float* __restrict__ coords,
                                              float4* __restrict__ cq,
                                              int* __restrict__ counts_g,
                                              int* __restrict__ starts_g,
                                              int* __restrict__ csr)
{
    __shared__ int cnt_s[NCELL];   // counts, then inclusive prefix
    __shared__ int cur_s[NCELL];   // scatter cursors
    const int b = blockIdx.x;
    const int t = threadIdx.x;
    cnt_s[t] = 0;
    __syncthreads();

    int mycell[4];
#pragma unroll
    for (int i = 0; i < 4; ++i) {
        const int pl = (i << 10) + t;          // local point id 0..4095
        const int p = (b << 12) + pl;
        const float x = coords[3 * p], y = coords[3 * p + 1], z = coords[3 * p + 2];
        cq[p] = make_float4(x, y, z, fmaf(z, z, fmaf(y, y, x * x)));
        mycell[i] = cell_of(x, y, z);
        atomicAdd(&cnt_s[mycell[i]], 1);
    }
    __syncthreads();

    const int count = cnt_s[t];
    int acc = count;
    for (int off = 1; off < NCELL; off <<= 1) {  // inclusive scan
        const int u = (t >= off) ? cnt_s[t - off] : 0;
        __syncthreads();
        acc += u; cnt_s[t] = acc;
        __syncthreads();
    }
    const int start = acc - count;               // exclusive prefix
    counts_g[(b << 10) + t] = count;
    starts_g[(b << 10) + t] = start;
    cur_s[t] = start;
    __syncthreads();

#pragma unroll
    for (int i = 0; i < 4; ++i) {
        const int pl = (i << 10) + t;
        const int pos = atomicAdd(&cur_s[mycell[i]], 1);
        csr[(b << 12) + pos] = pl;
    }
}

// ---- k1: x = relu(LN(inp@W1+b1)); a = x@W2[0:64]; c = x@W2[64:128]+b2-a; Sa = sum(a)
__global__ __launch_bounds__(256, 4) void k1_feat(
    const float* __restrict__ inp, const float* __restrict__ W1,
    const float* __restrict__ b1, const float* __restrict__ g1,
    const float* __restrict__ be1, const float* __restrict__ W2,
    const float* __restrict__ b2,
    float* __restrict__ a_buf, float* __restrict__ c_buf,
    float* __restrict__ Sa_buf)
{
    const int lane = threadIdx.x & 63;
    // readfirstlane: provably wave-uniform -> scalar loads for the 6 inputs
    const int p = __builtin_amdgcn_readfirstlane((blockIdx.x << 2) + (threadIdx.x >> 6));
    const float* ip = inp + (size_t)p * IDIM;
    float h = b1[lane];
#pragma unroll
    for (int j = 0; j < IDIM; ++j)
        h = fmaf(ip[j], W1[j * DIMS + lane], h);
    const float mean = wsum64(h) * (1.0f / DIMS);
    const float dv = h - mean;
    const float var = wsum64(dv * dv) * (1.0f / DIMS);
    const float x = fmaxf(dv * rsqrtf(var + LN_EPS) * g1[lane] + be1[lane], 0.0f);

    float a = 0.0f, cp = 0.0f;
    const int xi = __float_as_int(x);
#pragma unroll 8
    for (int j = 0; j < DIMS; ++j) {
        const int sj = __builtin_amdgcn_readlane(xi, j);
        if (sj != 0) {  // relu zeros -> uniform skip
            const float xj = __int_as_float(sj);
            a  = fmaf(xj, W2[j * DIMS + lane], a);
            cp = fmaf(xj, W2[(DIMS + j) * DIMS + lane], cp);
        }
    }
    const float c = cp + b2[lane] - a;
    a_buf[(size_t)p * DIMS + lane] = a;
    c_buf[(size_t)p * DIMS + lane] = c;
    const float sa = wsum64(a);
    if (lane == 0) Sa_buf[p] = sa;
}

// ---- k23: binned ball query + gather-LN-max. One wave per row.
__global__ __launch_bounds__(512, 4) void k23(
    const float4* __restrict__ cq, const float* __restrict__ DM,
    const float* __restrict__ a_buf, const float* __restrict__ c_buf,
    const float* __restrict__ Sa_buf, const int* __restrict__ starts,
    const int* __restrict__ counts, const int* __restrict__ csr,
    const float* __restrict__ g2, const float* __restrict__ be2,
    float* __restrict__ outp)
{
    __shared__ int p_tab[8][32];  // exclusive candidate-prefix per neighbor cell
    __shared__ int s_tab[8][32];  // csr start per neighbor cell
    __shared__ int hits[8][64];   // collected in-ball indices (unsorted)

    // XCD swizzle: 4096 blocks -> each XCD owns one batch (512 contiguous bids)
    const int bid = ((blockIdx.x & 7) << 9) + (blockIdx.x >> 3);
    const int lane = threadIdx.x & 63;
    const int w = threadIdx.x >> 6;
    const int row = (bid << 3) + w;
    const int b = row >> 12;
    const int n = row & (NN - 1);

    const float4* __restrict__ cqb = cq + ((size_t)b << 12);
    const float4 pn = cqb[n];
    // JAX weak-scalar promotion: (float)(0.1*0.1) = 0x3C23D70A, not 0.1f*0.1f.
    const float R2 = (float)(0.1 * 0.1);
    const float thr = R2 - pn.w;  // e = pm.w - 2*dot <= thr  <=>  within
    const float BAND = 1e-4f;     // recompute err <= ~3e-6 -> exact-DM fallback band
    const float* __restrict__ dmrow = DM + (size_t)row * NN;

    const int cx = min((int)(pn.x * INV_SIDE), 9);
    const int cy = min((int)(pn.y * INV_SIDE), 9);
    const int cz = min((int)(pn.z * INV_SIDE), 9);

    int cnt_i = 0, start_i = 0;
    if (lane < 27) {
        const int dx = lane / 9 - 1, dy = (lane / 3) % 3 - 1, dz = lane % 3 - 1;
        const int X = cx + dx, Y = cy + dy, Z = cz + dz;
        if ((unsigned)X <= 9u && (unsigned)Y <= 9u && (unsigned)Z <= 9u) {
            const int cid = (b << 10) + X * 100 + Y * 10 + Z;
            cnt_i = counts[cid];
            start_i = starts[cid];
        }
    }
    int incl = cnt_i;  // inclusive lane-scan of candidate counts
#pragma unroll
    for (int s = 1; s < 64; s <<= 1) {
        const int tv = __shfl_up(incl, s, 64);
        if (lane >= s) incl += tv;
    }
    const int T = __builtin_amdgcn_readlane(incl, 63);  // total candidates (~150)
    if (lane < 32) {
        p_tab[w][lane] = (lane < 27) ? (incl - cnt_i) : T;
        s_tab[w][lane] = start_i;
    }
    __syncthreads();

    int cnt = 0;
    for (int tb = 0; tb < T; tb += 64) {
        const int t = tb + lane;
        int mm = 0;
        bool within = false;
        if (t < T) {
            int c = 0;  // last cell with prefix <= t (5-step search over 32 entries)
#pragma unroll
            for (int s = 16; s >= 1; s >>= 1)
                if (p_tab[w][c + s] <= t) c += s;
            const int j = t - p_tab[w][c];
            mm = csr[(b << 12) + s_tab[w][c] + j];
            const float4 pm = cqb[mm];
            const float dot = fmaf(pn.z, pm.z, fmaf(pn.y, pm.y, pn.x * pm.x));
            const float e = fmaf(-2.0f, dot, pm.w);
            within = (e <= thr);
            if (fabsf(e - thr) <= BAND) within = (dmrow[mm] <= R2);  // exact
        }
        const unsigned long long msk = __ballot(within);
        if (within) {
            const int pos = cnt + __popcll(msk & ((1ull << lane) - 1ull));
            if (pos < 64) hits[w][pos] = mm;
        }
        cnt += __popcll(msk);
    }
    __syncthreads();

    int myidx = 0x7fffffff;
    if (cnt <= 64) {
        if (lane < cnt) myidx = hits[w][lane];
    } else {
        // overflow fallback (p ~ 0): exact ordered full scan, first 32
        cnt = 0;
        for (int mb = 0; mb < NN && cnt < KNB; mb += 64) {
            const int mmf = mb + lane;
            const float4 pm = cqb[mmf];
            const float dot = fmaf(pn.z, pm.z, fmaf(pn.y, pm.y, pn.x * pm.x));
            const float e = fmaf(-2.0f, dot, pm.w);
            bool wi = (e <= thr);
            if (fabsf(e - thr) <= BAND) wi = (dmrow[mmf] <= R2);
            unsigned long long m2 = __ballot(wi);
            while (m2 && cnt < KNB) {
                const int src = (int)__builtin_ctzll(m2);
                if (lane == cnt) myidx = mb + src;
                m2 &= m2 - 1;
                ++cnt;
            }
        }
    }
    sort64(myidx, lane);               // ascending; sentinels go high
    const int KK = min(cnt, KNB);      // members only; padding can't change a max

    // ---------------- Phase B ----------------
    const float cv = c_buf[(size_t)row * DIMS + lane];
    const float Sc = wsum64(cv);
    const float gg = g2[lane], bb = be2[lane];
    const float* __restrict__ abase = a_buf + ((size_t)(b << 12) * DIMS);
    const float* __restrict__ Sab = Sa_buf + (b << 12);
    const int mix = myidx;

    float om0 = 0.0f, om1 = 0.0f, om2 = 0.0f, om3 = 0.0f;
    for (int k = 0; k < KK; k += 4) {
        const int ka = min(k + 1, KK - 1);  // dup of a member: max unchanged
        const int kb2 = min(k + 2, KK - 1);
        const int kc = min(k + 3, KK - 1);
        const int m0 = __builtin_amdgcn_readlane(mix, k);
        const int m1 = __builtin_amdgcn_readlane(mix, ka);
        const int m2 = __builtin_amdgcn_readlane(mix, kb2);
        const int m3 = __builtin_amdgcn_readlane(mix, kc);
        const float mu0 = (Sab[m0] + Sc) * (1.0f / DIMS);
        const float mu1 = (Sab[m1] + Sc) * (1.0f / DIMS);
        const float mu2 = (Sab[m2] + Sc) * (1.0f / DIMS);
        const float mu3 = (Sab[m3] + Sc) * (1.0f / DIMS);
        const float d0 = abase[(size_t)m0 * DIMS + lane] + cv - mu0;
        const float d1 = abase[(size_t)m1 * DIMS + lane] + cv - mu1;
        const float d2 = abase[(size_t)m2 * DIMS + lane] + cv - mu2;
        const float d3 = abase[(size_t)m3 * DIMS + lane] + cv - mu3;
        const float q0 = wsum64(d0 * d0);
        const float q1 = wsum64(d1 * d1);
        const float q2 = wsum64(d2 * d2);
        const float q3 = wsum64(d3 * d3);
        const float y0 = d0 * rsqrtf(q0 * (1.0f / DIMS) + LN_EPS) * gg + bb;
        const float y1 = d1 * rsqrtf(q1 * (1.0f / DIMS) + LN_EPS) * gg + bb;
        const float y2 = d2 * rsqrtf(q2 * (1.0f / DIMS) + LN_EPS) * gg + bb;
        const float y3 = d3 * rsqrtf(q3 * (1.0f / DIMS) + LN_EPS) * gg + bb;
        om0 = fmaxf(om0, y0);
        om1 = fmaxf(om1, y1);
        om2 = fmaxf(om2, y2);
        om3 = fmaxf(om3, y3);
    }
    outp[(size_t)row * DIMS + lane] =
        fmaxf(fmaxf(fmaxf(om0, om1), fmaxf(om2, om3)), 0.0f);
}

extern "C" void kernel_launch(void* const* d_in, const int* in_sizes, int n_in,
                              void* d_out, int out_size, void* d_ws, size_t ws_size,
                              hipStream_t stream)
{
    const float* inp    = (const float*)d_in[0];
    const float* coords = (const float*)d_in[1];
    const float* DM     = (const float*)d_in[2];
    const float* W1     = (const float*)d_in[3];
    const float* b1v    = (const float*)d_in[4];
    const float* g1     = (const float*)d_in[5];
    const float* be1    = (const float*)d_in[6];
    const float* W2     = (const float*)d_in[7];
    const float* b2v    = (const float*)d_in[8];
    const float* g2     = (const float*)d_in[9];
    const float* be2    = (const float*)d_in[10];
    float* out = (float*)d_out;

    char* ws = (char*)d_ws;
    size_t off = 0;
    float*  a_buf  = (float*)(ws + off); off += (size_t)BN * DIMS * 4;   // 8 MB
    float*  c_buf  = (float*)(ws + off); off += (size_t)BN * DIMS * 4;   // 8 MB
    float*  Sa_buf = (float*)(ws + off); off += (size_t)BN * 4;          // 128 KB
    float4* cq     = (float4*)(ws + off); off += (size_t)BN * 16;        // 512 KB
    int*    counts = (int*)(ws + off); off += (size_t)BB * NCELL * 4;    // 32 KB
    int*    starts = (int*)(ws + off); off += (size_t)BB * NCELL * 4;    // 32 KB
    int*    csr    = (int*)(ws + off); off += (size_t)BN * 4;            // 128 KB

    k_csr<<<dim3(BB), dim3(1024), 0, stream>>>(coords, cq, counts, starts, csr);
    k1_feat<<<dim3(BN / 4), dim3(256), 0, stream>>>(
        inp, W1, b1v, g1, be1, W2, b2v, a_buf, c_buf, Sa_buf);
    k23<<<dim3(BN / 8), dim3(512), 0, stream>>>(
        cq, DM, a_buf, c_buf, Sa_buf, starts, counts, csr, g2, be2, out);
}